// Round 8
// baseline (73.630 us; speedup 1.0000x reference)
//
#include <hip/hip_runtime.h>
#include <math.h>

// Problem constants (reference is fixed-shape).
#define B_ 16
#define N_ 2048
#define D_ 128

typedef __attribute__((ext_vector_type(8))) short bf16x8;   // 8 bf16 = 4 VGPRs
typedef __attribute__((ext_vector_type(4))) float f32x4;

__device__ __forceinline__ unsigned short f2bf(float f) {
    unsigned u = __float_as_uint(f);
    u += 0x7FFFu + ((u >> 16) & 1u);
    return (unsigned short)(u >> 16);
}

__device__ __forceinline__ unsigned minkey(float f) {
    // order-preserving uint encoding of float (for atomicMin): exact, assoc.
    unsigned u = __float_as_uint(f);
    return u ^ ((unsigned)((int)u >> 31) | 0x80000000u);
}

// Fragment-order element offset within a 128x128 bf16 tile.
// Chunks of 8 k-elems laid out so that one MFMA B-fragment read instruction
// (fixed ks/half/n; lane ln) covers 1024 CONTIGUOUS bytes: conflict-free
// ds_read_b128 by construction (R4 counter: old layout = +8.0 cy/read).
__device__ __forceinline__ int frag_off(int c, int k) {
    return ((((k >> 5) * 8 + (c >> 6) * 4 + ((c >> 4) & 3)) * 64
             + ((k >> 3) & 3) * 16 + (c & 15)) * 8) + (k & 7);
}

// ---------------------------------------------------------------------------
// K1: fp32 -> bf16 in fragment-ordered tiles + fp32 squared norms + per-call
// re-init of pmk keys and the done-counter (harness does not re-poison
// between replays; ALL workspace state must be rebuilt every call).
// 2048 WGs x 16 rows (dispatch-cost trim vs 8192 WGs: ~0.6ns/WG).
// ---------------------------------------------------------------------------
__global__ __launch_bounds__(256) void prep_kernel(
        const float* __restrict__ X, unsigned short* __restrict__ Xs,
        float* __restrict__ sqn, unsigned* __restrict__ pmk,
        unsigned* __restrict__ fincnt) {
    int wv = threadIdx.x >> 6, ln = threadIdx.x & 63;
    int row0 = blockIdx.x * 16 + wv * 4;
    #pragma unroll
    for (int i = 0; i < 4; ++i) {
        int row = row0 + i;
        const float* src = X + (size_t)row * D_;
        float2 v = *(const float2*)(src + ln * 2);
        unsigned short h0 = f2bf(v.x), h1 = f2bf(v.y);
        float f0 = __uint_as_float((unsigned)h0 << 16);
        float f1 = __uint_as_float((unsigned)h1 << 16);
        float s = f0 * f0 + f1 * f1;
        #pragma unroll
        for (int o = 32; o; o >>= 1) s += __shfl_xor(s, o, 64);
        int c   = row & 127;                   // row within its 128-row tile
        int off = frag_off(c, ln * 2);         // k&7 even -> pair stays intact
        *(unsigned*)(Xs + (((size_t)(row >> 7)) << 14) + off) =
            (unsigned)h0 | ((unsigned)h1 << 16);
        if (ln == 0) { sqn[row] = s; pmk[row] = 0xFFFFFFFFu; }
    }
    if (blockIdx.x == 0 && threadIdx.x == 0) *fincnt = 0u;
}

// ---------------------------------------------------------------------------
// K2: fused Gram + row-min + (last-WG) finalize.  512 WGs = 16 batches x
// 8 i-tiles (256 rows) x 4 j-quarters.  WG = 256 thr / 4 waves; wave owns
// 64 i-rows with A-fragments in registers.  j-tiles (fragment-ordered 32 KB)
// double-buffered in LDS via linear global_load_lds; every B-fragment
// ds_read_b128 is contiguous (conflict-free, imm-offset addressing).
//
// Finalize fusion is FENCE-FREE (round-4 lesson: per-WG __threadfence =
// buffer_inv/wbl2 L2-invalidate storm, 82 us).  Correctness argument:
//  - pmk is written ONLY via atomicMin -> device-coherent point [m20];
//  - __syncthreads() drains each wave's vmcnt (compiler emits s_waitcnt
//    vmcnt(0) before s_barrier), so by the fincnt atomicAdd all this WG's
//    mins are globally performed;
//  - the last WG (old==511) therefore sees final pmk via agent-scope
//    RELAXED ATOMIC loads (bypass non-coherent XCD L2). No cache flush.
// Exactly one WG per call finalizes -> deterministic output.
// ---------------------------------------------------------------------------
__device__ __forceinline__ void stage_tile(const unsigned short* gsrc,
                                           unsigned short* lds, int wv, int ln) {
    // 32 KB fragment-ordered tile, 4 waves: each wave copies 8 KB linearly.
    const char* g = (const char*)gsrc + wv * 8192 + ln * 16;
    char*       l = (char*)lds + wv * 8192;          // wave-uniform LDS base
    #pragma unroll
    for (int i = 0; i < 8; ++i)
        __builtin_amdgcn_global_load_lds(
            (const __attribute__((address_space(1))) unsigned int*)(g + i * 1024),
            (__attribute__((address_space(3))) unsigned int*)(l + i * 1024),
            16, 0, 0);
}

__global__ __launch_bounds__(256, 2) void nnd_kernel(
        const unsigned short* __restrict__ Xs, const float* __restrict__ sqn,
        unsigned* __restrict__ pmk, unsigned* __restrict__ fincnt,
        float* __restrict__ out) {
    __shared__ unsigned short Xj[2][128 * D_];   // 2 x 32 KB -> 2 WGs/CU
    __shared__ double fa1[4], fa2[4];
    __shared__ int lastflag;

    // XCD-chunked remap (512 = 8 x 64, bijective): 64 consecutive ids per
    // XCD -> 2 batches (1 MB of Xs) per XCD L2.
    int wg  = (int)blockIdx.x;
    int id  = (wg & 7) * 64 + (wg >> 3);
    int b   = id >> 5;           // 32 ids per batch
    int sub = id & 31;
    int it  = sub >> 2;          // 256-row i-tile (8 per batch)
    int jh  = sub & 3;           // 512-col j-quarter (4 tiles of 128)

    int tid = threadIdx.x, wv = tid >> 6, ln = tid & 63;
    int lr = ln & 15;                 // fragment row/col lane index
    int kg = (ln >> 4) * 8;           // A/B fragment k-group offset
    int rg = (ln >> 4) * 4;           // C/D fragment row-group offset

    const unsigned short* Xb  = Xs  + (size_t)b * N_ * D_;
    const float*          sqb = sqn + b * N_;
    int ibase = it * 256 + wv * 64;   // this wave's first i-row

    // A fragments: 64 rows x K=128 from the fragment-ordered global layout.
    bf16x8 Af[4][4];
    #pragma unroll
    for (int m = 0; m < 4; ++m) {
        int r = ibase + m * 16 + lr;
        const unsigned short* tp = Xb + (((size_t)(r >> 7)) << 14);
        int c = r & 127;
        #pragma unroll
        for (int ks = 0; ks < 4; ++ks)
            Af[m][ks] = *(const bf16x8*)(tp + frag_off(c, ks * 32 + kg));
    }

    float rmin[16];
    #pragma unroll
    for (int q = 0; q < 16; ++q) rmin[q] = 1e30f;
    const f32x4 zero4 = {0.f, 0.f, 0.f, 0.f};

    stage_tile(Xb + ((size_t)(jh * 4) << 14), Xj[0], wv, ln);
    __syncthreads();

    for (int t = 0; t < 4; ++t) {
        int jt = jh * 4 + t, cur = t & 1;
        if (t < 3)
            stage_tile(Xb + ((size_t)(jt + 1) << 14), Xj[cur ^ 1], wv, ln);

        const unsigned short* L = &Xj[cur][0];
        bool dtile = (jt >> 1) == it;      // j-tile inside this i-256-range

        #pragma unroll
        for (int half = 0; half < 2; ++half) {       // 64-col halves
            float nj[4];
            #pragma unroll
            for (int n = 0; n < 4; ++n)
                nj[n] = sqb[jt * 128 + half * 64 + n * 16 + lr];

            f32x4 acc[4][4];
            #pragma unroll
            for (int ks = 0; ks < 4; ++ks) {
                bf16x8 Bf[4];
                #pragma unroll
                for (int n = 0; n < 4; ++n)
                    Bf[n] = *(const bf16x8*)(
                        &L[((ks * 8 + half * 4 + n) * 64 + ln) * 8]);
                #pragma unroll
                for (int m = 0; m < 4; ++m)
                    #pragma unroll
                    for (int n = 0; n < 4; ++n)
                        acc[m][n] = __builtin_amdgcn_mfma_f32_16x16x32_bf16(
                            Af[m][ks], Bf[n], ks ? acc[m][n] : zero4, 0, 0, 0);
            }

            // Fold min_j (n_j - 2 g).  C/D: col = lane&15, row = rg + reg.
            if (!dtile) {
                #pragma unroll
                for (int m = 0; m < 4; ++m)
                    #pragma unroll
                    for (int rr = 0; rr < 4; ++rr) {
                        float t0 = fmaf(-2.f, acc[m][0][rr], nj[0]);
                        float t1 = fmaf(-2.f, acc[m][1][rr], nj[1]);
                        float t2 = fmaf(-2.f, acc[m][2][rr], nj[2]);
                        float t3 = fmaf(-2.f, acc[m][3][rr], nj[3]);
                        rmin[m * 4 + rr] = fminf(rmin[m * 4 + rr],
                                          fminf(fminf(t0, t1), fminf(t2, t3)));
                    }
            } else {
                #pragma unroll
                for (int m = 0; m < 4; ++m)
                    #pragma unroll
                    for (int rr = 0; rr < 4; ++rr) {
                        int ir = ibase + m * 16 + rg + rr;       // global row
                        int jc = jt * 128 + half * 64 + lr;      // global col
                        float t0 = (ir == jc)      ? 1e30f
                                   : fmaf(-2.f, acc[m][0][rr], nj[0]);
                        float t1 = (ir == jc + 16) ? 1e30f
                                   : fmaf(-2.f, acc[m][1][rr], nj[1]);
                        float t2 = (ir == jc + 32) ? 1e30f
                                   : fmaf(-2.f, acc[m][2][rr], nj[2]);
                        float t3 = (ir == jc + 48) ? 1e30f
                                   : fmaf(-2.f, acc[m][3][rr], nj[3]);
                        rmin[m * 4 + rr] = fminf(rmin[m * 4 + rr],
                                          fminf(fminf(t0, t1), fminf(t2, t3)));
                    }
            }
        }
        __syncthreads();
    }

    // Min across the 16 column-lanes, then one atomicMin per row.
    #pragma unroll
    for (int o = 1; o < 16; o <<= 1)
        #pragma unroll
        for (int q = 0; q < 16; ++q)
            rmin[q] = fminf(rmin[q], __shfl_xor(rmin[q], o, 64));
    if (lr == 0) {
        #pragma unroll
        for (int m = 0; m < 4; ++m)
            #pragma unroll
            for (int rr = 0; rr < 4; ++rr) {
                int row = ibase + m * 16 + rg + rr;
                atomicMin(pmk + b * N_ + row, minkey(rmin[m * 4 + rr]));
            }
    }

    // ---- fence-free last-WG finalize ----
    __syncthreads();   // drains vmcnt per wave: all this WG's mins performed
    if (tid == 0) {
        unsigned old = atomicAdd(fincnt, 1u);   // device-coherent by default
        lastflag = (old == 511u);
    }
    __syncthreads();
    if (lastflag) {
        const int M = B_ * N_;
        double s1 = 0.0, s2 = 0.0;
        for (int i = tid; i < M; i += 256) {
            unsigned key = __hip_atomic_load(&pmk[i], __ATOMIC_RELAXED,
                                             __HIP_MEMORY_SCOPE_AGENT);
            unsigned u = (key & 0x80000000u) ? (key ^ 0x80000000u) : ~key;
            float d2 = sqn[i] + __uint_as_float(u);  // sqn: prior kernel, coherent
            float x32 = sqrtf(fmaxf(d2, 0.f));
            double x = (double)x32;
            s1 += x; s2 += x * x;
        }
        #pragma unroll
        for (int o = 32; o; o >>= 1) {
            s1 += __shfl_down(s1, o, 64);
            s2 += __shfl_down(s2, o, 64);
        }
        if (ln == 0) { fa1[wv] = s1; fa2[wv] = s2; }
        __syncthreads();
        if (tid == 0) {
            double T1 = 0.0, T2 = 0.0;
            #pragma unroll
            for (int w = 0; w < 4; ++w) { T1 += fa1[w]; T2 += fa2[w]; }
            double mean = T1 / M;
            double var  = (T2 - T1 * T1 / M) / (M - 1);
            double stdv = var > 0.0 ? sqrt(var) : 0.0;
            double cv   = (mean > 1e-8) ? stdv / fmax(mean, 1e-8) : 0.0;
            out[0] = (float)mean;
            out[1] = (float)stdv;
            out[2] = (float)cv;
        }
    }
}

extern "C" void kernel_launch(void* const* d_in, const int* in_sizes, int n_in,
                              void* d_out, int out_size, void* d_ws, size_t ws_size,
                              hipStream_t stream) {
    const float* X = (const float*)d_in[0];
    const size_t XS_BYTES = (size_t)B_ * N_ * D_ * 2;        // 8 MB
    char* ws = (char*)d_ws;
    unsigned short* Xs     = (unsigned short*)ws;
    float*          sqn    = (float*)(ws + XS_BYTES);
    unsigned*       pmk    = (unsigned*)(ws + XS_BYTES + (size_t)B_ * N_ * 4);
    unsigned*       fincnt = (unsigned*)(ws + XS_BYTES + (size_t)B_ * N_ * 8);
    float*          out    = (float*)d_out;

    prep_kernel<<<B_ * N_ / 16, 256, 0, stream>>>(X, Xs, sqn, pmk, fincnt);
    nnd_kernel<<<512, 256, 0, stream>>>(Xs, sqn, pmk, fincnt, out);
}

// Round 9
// 55.016 us; speedup vs baseline: 1.3383x; 1.3383x over previous
//
#include <hip/hip_runtime.h>
#include <math.h>

// Problem constants (reference is fixed-shape).
#define B_ 16
#define N_ 2048
#define D_ 128

typedef __attribute__((ext_vector_type(8))) short bf16x8;   // 8 bf16 = 4 VGPRs
typedef __attribute__((ext_vector_type(4))) float f32x4;

__device__ __forceinline__ unsigned short f2bf(float f) {
    unsigned u = __float_as_uint(f);
    u += 0x7FFFu + ((u >> 16) & 1u);
    return (unsigned short)(u >> 16);
}

__device__ __forceinline__ unsigned minkey(float f) {
    // order-preserving uint encoding of float (for atomicMin): exact, assoc.
    unsigned u = __float_as_uint(f);
    return u ^ ((unsigned)((int)u >> 31) | 0x80000000u);
}

// Fragment-order element offset within a 128x128 bf16 tile: one MFMA
// fragment-read (fixed ks/half/n) = 64 lanes x 16 B CONTIGUOUS (1 KB).
__device__ __forceinline__ int frag_off(int c, int k) {
    return ((((k >> 5) * 8 + (c >> 6) * 4 + ((c >> 4) & 3)) * 64
             + ((k >> 3) & 3) * 16 + (c & 15)) * 8) + (k & 7);
}

// ---------------------------------------------------------------------------
// K1: fp32 -> bf16 fragment-ordered tiles + fp32 squared norms + per-call
// re-init of pmk / fincnt (harness never re-poisons between replays).
// ---------------------------------------------------------------------------
__global__ __launch_bounds__(256) void prep_kernel(
        const float* __restrict__ X, unsigned short* __restrict__ Xs,
        float* __restrict__ sqn, unsigned* __restrict__ pmk,
        unsigned* __restrict__ fincnt) {
    int wv = threadIdx.x >> 6, ln = threadIdx.x & 63;
    int row0 = blockIdx.x * 16 + wv * 4;
    #pragma unroll
    for (int i = 0; i < 4; ++i) {
        int row = row0 + i;
        const float* src = X + (size_t)row * D_;
        float2 v = *(const float2*)(src + ln * 2);
        unsigned short h0 = f2bf(v.x), h1 = f2bf(v.y);
        float f0 = __uint_as_float((unsigned)h0 << 16);
        float f1 = __uint_as_float((unsigned)h1 << 16);
        float s = f0 * f0 + f1 * f1;
        #pragma unroll
        for (int o = 32; o; o >>= 1) s += __shfl_xor(s, o, 64);
        int c   = row & 127;
        int off = frag_off(c, ln * 2);     // k&7 even -> bf16 pair stays intact
        *(unsigned*)(Xs + (((size_t)(row >> 7)) << 14) + off) =
            (unsigned)h0 | ((unsigned)h1 << 16);
        if (ln == 0) { sqn[row] = s; pmk[row] = 0xFFFFFFFFu; }
    }
    if (blockIdx.x == 0 && threadIdx.x == 0) *fincnt = 0u;
}

// ---------------------------------------------------------------------------
// K2: fused Gram + row-min, LDS-FREE.  Round-8 lesson: Xs is 512 KB/batch
// (L2-fits, 2 batches/XCD); LDS staging + per-step full-drain barriers at
// 8 waves/CU was the stall (nnd ~28 us, MfmaUtil 9%).  Here B-fragments are
// loaded DIRECTLY from the fragment-ordered global layout: each load is
// 64 lanes x 16 B contiguous (1 KB, coalesced, L1/L2-hit; the WG's 4 waves
// read the same fragments near-simultaneously -> L1 reuse).  No __syncthreads
// in the sweep, no LDS -> occupancy is VGPR-bound (~3 waves/SIMD, 12/CU).
// Grid 1024 = b(16) x it(8: 256-row i-tile) x jo(8: 256-col octant).
// acc processed in n-pairs to bound VGPR; nj preloaded.
// Row-mins merge via uint-keyed atomicMin (exact, associative, deterministic).
// NO device-scope fences (round-4 lesson).
// ---------------------------------------------------------------------------
__global__ __launch_bounds__(256, 3) void nnd_kernel(
        const unsigned short* __restrict__ Xs, const float* __restrict__ sqn,
        unsigned* __restrict__ pmk) {
    // XCD-chunked remap (1024 = 8 x 128, bijective): 128 consecutive ids per
    // XCD -> 2 batches (1 MB of Xs) per XCD L2.
    int wg  = (int)blockIdx.x;
    int id  = (wg & 7) * 128 + (wg >> 3);
    int b   = id >> 6;           // 64 ids per batch
    int sub = id & 63;
    int it  = sub >> 3;          // 256-row i-tile (8 per batch)
    int jo  = sub & 7;           // 256-col j-octant (2 tiles of 128)

    int tid = threadIdx.x, wv = tid >> 6, ln = tid & 63;
    int lr = ln & 15;                 // fragment row/col lane index
    int kg = (ln >> 4) * 8;           // A/B fragment k-group offset
    int rg = (ln >> 4) * 4;           // C/D fragment row-group offset

    const unsigned short* Xb  = Xs  + (size_t)b * N_ * D_;
    const float*          sqb = sqn + b * N_;
    int ibase = it * 256 + wv * 64;   // this wave's first i-row

    // A fragments: 64 rows x K=128, registers for the whole sweep.
    bf16x8 Af[4][4];
    #pragma unroll
    for (int m = 0; m < 4; ++m) {
        int r = ibase + m * 16 + lr;
        const unsigned short* tp = Xb + (((size_t)(r >> 7)) << 14);
        int c = r & 127;
        #pragma unroll
        for (int ks = 0; ks < 4; ++ks)
            Af[m][ks] = *(const bf16x8*)(tp + frag_off(c, ks * 32 + kg));
    }

    // nj preload: this lane's 16 column-norm values across the octant.
    float njv[2][2][4];
    #pragma unroll
    for (int t = 0; t < 2; ++t)
        #pragma unroll
        for (int half = 0; half < 2; ++half)
            #pragma unroll
            for (int n = 0; n < 4; ++n)
                njv[t][half][n] =
                    sqb[(jo * 2 + t) * 128 + half * 64 + n * 16 + lr];

    float rmin[16];
    #pragma unroll
    for (int q = 0; q < 16; ++q) rmin[q] = 1e30f;
    const f32x4 zero4 = {0.f, 0.f, 0.f, 0.f};

    #pragma unroll
    for (int t = 0; t < 2; ++t) {
        int jt = jo * 2 + t;
        const unsigned short* tp = Xb + ((size_t)jt << 14);   // j-tile base
        bool dtile = (jt >> 1) == it;    // j-tile inside this i-256-range

        #pragma unroll
        for (int half = 0; half < 2; ++half) {
            #pragma unroll
            for (int np = 0; np < 2; ++np) {         // n-pair: bounds VGPR
                f32x4 acc[4][2];
                #pragma unroll
                for (int ks = 0; ks < 4; ++ks) {
                    bf16x8 Bf0 = *(const bf16x8*)(
                        tp + (((ks * 8 + half * 4 + np * 2 + 0) * 64 + ln) * 8));
                    bf16x8 Bf1 = *(const bf16x8*)(
                        tp + (((ks * 8 + half * 4 + np * 2 + 1) * 64 + ln) * 8));
                    #pragma unroll
                    for (int m = 0; m < 4; ++m) {
                        acc[m][0] = __builtin_amdgcn_mfma_f32_16x16x32_bf16(
                            Af[m][ks], Bf0, ks ? acc[m][0] : zero4, 0, 0, 0);
                        acc[m][1] = __builtin_amdgcn_mfma_f32_16x16x32_bf16(
                            Af[m][ks], Bf1, ks ? acc[m][1] : zero4, 0, 0, 0);
                    }
                }
                float nj0 = njv[t][half][np * 2 + 0];
                float nj1 = njv[t][half][np * 2 + 1];
                if (!dtile) {
                    #pragma unroll
                    for (int m = 0; m < 4; ++m)
                        #pragma unroll
                        for (int rr = 0; rr < 4; ++rr) {
                            float t0 = fmaf(-2.f, acc[m][0][rr], nj0);
                            float t1 = fmaf(-2.f, acc[m][1][rr], nj1);
                            rmin[m * 4 + rr] =
                                fminf(rmin[m * 4 + rr], fminf(t0, t1));
                        }
                } else {
                    #pragma unroll
                    for (int m = 0; m < 4; ++m)
                        #pragma unroll
                        for (int rr = 0; rr < 4; ++rr) {
                            int ir = ibase + m * 16 + rg + rr;     // global row
                            int jc = jt * 128 + half * 64 + np * 32 + lr;
                            float t0 = (ir == jc)      ? 1e30f
                                       : fmaf(-2.f, acc[m][0][rr], nj0);
                            float t1 = (ir == jc + 16) ? 1e30f
                                       : fmaf(-2.f, acc[m][1][rr], nj1);
                            rmin[m * 4 + rr] =
                                fminf(rmin[m * 4 + rr], fminf(t0, t1));
                        }
                }
            }
        }
    }

    // Min across the 16 column-lanes, then one atomicMin per row.
    #pragma unroll
    for (int o = 1; o < 16; o <<= 1)
        #pragma unroll
        for (int q = 0; q < 16; ++q)
            rmin[q] = fminf(rmin[q], __shfl_xor(rmin[q], o, 64));
    if (lr == 0) {
        #pragma unroll
        for (int m = 0; m < 4; ++m)
            #pragma unroll
            for (int rr = 0; rr < 4; ++rr) {
                int row = ibase + m * 16 + rg + rr;
                atomicMin(pmk + b * N_ + row, minkey(rmin[m * 4 + rr]));
            }
    }
}

// ---------------------------------------------------------------------------
// K3: decode keys -> nnd; mean / unbiased std / CV.  64 WGs x 512 thr (one
// pmk load per thread, fully parallel — round-8 lesson: a single-WG reader
// serializes 32K high-latency loads = +40 us).  Last WG sums the 64 slots.
// ---------------------------------------------------------------------------
__global__ __launch_bounds__(512) void finalize_kernel(
        const unsigned* __restrict__ pmk, const float* __restrict__ sqn,
        double* __restrict__ slots, unsigned* __restrict__ fincnt,
        float* __restrict__ out) {
    const int M = B_ * N_;
    int r = blockIdx.x * 512 + (int)threadIdx.x;
    unsigned key = pmk[r];
    unsigned u   = (key & 0x80000000u) ? (key ^ 0x80000000u) : ~key;
    float d2 = sqn[r] + __uint_as_float(u);
    float x32 = sqrtf(fmaxf(d2, 0.f));       // reference uses f32 sqrt too
    double x = (double)x32;
    double s1 = x, s2 = x * x;
    #pragma unroll
    for (int o = 32; o; o >>= 1) {
        s1 += __shfl_down(s1, o, 64);
        s2 += __shfl_down(s2, o, 64);
    }
    __shared__ double a1[8], a2[8];
    int wv = threadIdx.x >> 6, ln = threadIdx.x & 63;
    if (ln == 0) { a1[wv] = s1; a2[wv] = s2; }
    __syncthreads();
    if (threadIdx.x == 0) {
        double S1 = 0.0, S2 = 0.0;
        #pragma unroll
        for (int w = 0; w < 8; ++w) { S1 += a1[w]; S2 += a2[w]; }
        slots[blockIdx.x * 2]     = S1;
        slots[blockIdx.x * 2 + 1] = S2;
        __threadfence();
        unsigned old = atomicAdd(fincnt, 1u);
        if (old == 63u) {
            double T1 = 0.0, T2 = 0.0;
            for (int w = 0; w < 64; ++w) {
                T1 += __hip_atomic_load(&slots[w * 2],     __ATOMIC_RELAXED,
                                        __HIP_MEMORY_SCOPE_AGENT);
                T2 += __hip_atomic_load(&slots[w * 2 + 1], __ATOMIC_RELAXED,
                                        __HIP_MEMORY_SCOPE_AGENT);
            }
            double mean = T1 / M;
            double var  = (T2 - T1 * T1 / M) / (M - 1);
            double stdv = var > 0.0 ? sqrt(var) : 0.0;
            double cv   = (mean > 1e-8) ? stdv / fmax(mean, 1e-8) : 0.0;
            out[0] = (float)mean;
            out[1] = (float)stdv;
            out[2] = (float)cv;
        }
    }
}

extern "C" void kernel_launch(void* const* d_in, const int* in_sizes, int n_in,
                              void* d_out, int out_size, void* d_ws, size_t ws_size,
                              hipStream_t stream) {
    const float* X = (const float*)d_in[0];
    const size_t XS_BYTES = (size_t)B_ * N_ * D_ * 2;        // 8 MB
    char* ws = (char*)d_ws;
    unsigned short* Xs     = (unsigned short*)ws;
    float*          sqn    = (float*)(ws + XS_BYTES);
    unsigned*       pmk    = (unsigned*)(ws + XS_BYTES + (size_t)B_ * N_ * 4);
    double*         slots  = (double*)(ws + XS_BYTES + (size_t)B_ * N_ * 8);
    unsigned*       fincnt = (unsigned*)(ws + XS_BYTES + (size_t)B_ * N_ * 8 + 1024);
    float*          out    = (float*)d_out;

    prep_kernel<<<B_ * N_ / 16, 256, 0, stream>>>(X, Xs, sqn, pmk, fincnt);
    nnd_kernel<<<1024, 256, 0, stream>>>(Xs, sqn, pmk);
    finalize_kernel<<<B_ * N_ / 512, 512, 0, stream>>>(pmk, sqn, slots, fincnt, out);
}

// Round 10
// 37.384 us; speedup vs baseline: 1.9696x; 1.4716x over previous
//
#include <hip/hip_runtime.h>
#include <math.h>

// Problem constants (reference is fixed-shape).
#define B_ 16
#define N_ 2048
#define D_ 128

typedef __attribute__((ext_vector_type(8))) short bf16x8;   // 8 bf16 = 4 VGPRs
typedef __attribute__((ext_vector_type(4))) float f32x4;

__device__ __forceinline__ unsigned short f2bf(float f) {
    unsigned u = __float_as_uint(f);
    u += 0x7FFFu + ((u >> 16) & 1u);
    return (unsigned short)(u >> 16);
}

__device__ __forceinline__ unsigned minkey(float f) {
    // order-preserving uint encoding of float (for atomicMin): exact, assoc.
    unsigned u = __float_as_uint(f);
    return u ^ ((unsigned)((int)u >> 31) | 0x80000000u);
}

// Fragment-order element offset within a 128x128 bf16 tile: one MFMA
// fragment-read (fixed fragment group g) = 64 lanes x 16 B CONTIGUOUS (1 KB).
__device__ __forceinline__ int frag_off(int c, int k) {
    return ((((k >> 5) * 8 + (c >> 6) * 4 + ((c >> 4) & 3)) * 64
             + ((k >> 3) & 3) * 16 + (c & 15)) * 8) + (k & 7);
}

// ---------------------------------------------------------------------------
// K1: fp32 -> bf16 fragment-ordered tiles + fp32 squared norms + per-call
// re-init of pmk / fincnt (harness never re-poisons between replays).
// ---------------------------------------------------------------------------
__global__ __launch_bounds__(256) void prep_kernel(
        const float* __restrict__ X, unsigned short* __restrict__ Xs,
        float* __restrict__ sqn, unsigned* __restrict__ pmk,
        unsigned* __restrict__ fincnt) {
    int wv = threadIdx.x >> 6, ln = threadIdx.x & 63;
    int row0 = blockIdx.x * 16 + wv * 4;
    #pragma unroll
    for (int i = 0; i < 4; ++i) {
        int row = row0 + i;
        const float* src = X + (size_t)row * D_;
        float2 v = *(const float2*)(src + ln * 2);
        unsigned short h0 = f2bf(v.x), h1 = f2bf(v.y);
        float f0 = __uint_as_float((unsigned)h0 << 16);
        float f1 = __uint_as_float((unsigned)h1 << 16);
        float s = f0 * f0 + f1 * f1;
        #pragma unroll
        for (int o = 32; o; o >>= 1) s += __shfl_xor(s, o, 64);
        int c   = row & 127;
        int off = frag_off(c, ln * 2);     // k&7 even -> bf16 pair stays intact
        *(unsigned*)(Xs + (((size_t)(row >> 7)) << 14) + off) =
            (unsigned)h0 | ((unsigned)h1 << 16);
        if (ln == 0) { sqn[row] = s; pmk[row] = 0xFFFFFFFFu; }
    }
    if (blockIdx.x == 0 && threadIdx.x == 0) *fincnt = 0u;
}

// ---------------------------------------------------------------------------
// K2: fused Gram + row-min, reg-staged B with explicit 1-step-ahead prefetch.
// Round-9 lessons: (1) grid must be ONE scheduling round (512 WGs @ 2/CU) or
// late WGs land on arbitrary XCDs and thrash L2 (FETCH 4.3 -> 23 MB);
// (2) the compiler does NOT hoist B-loads across MFMA blocks by itself
// (VGPR_Count 84) -> explicit register double-buffer.
// Grid 512 = b(16) x it(8: 256-row i-tile) x jo(4: 512-col quarter).
// Wave = 64 i-rows; A-frags (64 VGPR) + acc + 2x4 B-frag buffers ~ 165 VGPR.
// 32 flat sub-steps: s -> (t, half, np, kh); each sub-step prefetches the
// next 4 B-frags (1 KB coalesced each, L1-shared across the WG's 4 waves),
// then issues 16 MFMAs.  Raw s_barrier (no drain) at tile boundaries keeps
// waves in lockstep for L1 reuse.  No LDS, no __syncthreads, no fences.
// Row-mins merge via uint-keyed atomicMin (exact, associative, determ.).
// ---------------------------------------------------------------------------
__global__ __launch_bounds__(256, 2) void nnd_kernel(
        const unsigned short* __restrict__ Xs, const float* __restrict__ sqn,
        unsigned* __restrict__ pmk) {
    // XCD-chunked remap (512 = 8 x 64, bijective): 64 consecutive ids per
    // XCD -> 2 batches (1 MB of Xs) per XCD L2.  Valid because the whole
    // grid is co-resident (one round).
    int wg  = (int)blockIdx.x;
    int id  = (wg & 7) * 64 + (wg >> 3);
    int b   = id >> 5;           // 32 ids per batch
    int sub = id & 31;
    int it  = sub >> 2;          // 256-row i-tile (8 per batch)
    int jo  = sub & 3;           // 512-col j-quarter (4 tiles of 128)

    int tid = threadIdx.x, wv = tid >> 6, ln = tid & 63;
    int lr = ln & 15;                 // fragment row/col lane index
    int kg = (ln >> 4) * 8;           // A fragment k-group offset
    int rg = (ln >> 4) * 4;           // C/D fragment row-group offset

    const unsigned short* Xb  = Xs  + (size_t)b * N_ * D_;
    const float*          sqb = sqn + b * N_;
    int ibase = it * 256 + wv * 64;   // this wave's first i-row

    // A fragments: 64 rows x K=128, registers for the whole sweep (coalesced
    // 1 KB loads from the fragment-ordered layout).
    bf16x8 Af[4][4];
    #pragma unroll
    for (int m = 0; m < 4; ++m) {
        int r = ibase + m * 16 + lr;
        const unsigned short* tp = Xb + (((size_t)(r >> 7)) << 14);
        int c = r & 127;
        #pragma unroll
        for (int ks = 0; ks < 4; ++ks)
            Af[m][ks] = *(const bf16x8*)(tp + frag_off(c, ks * 32 + kg));
    }

    float rmin[16];
    #pragma unroll
    for (int q = 0; q < 16; ++q) rmin[q] = 1e30f;
    const f32x4 zero4 = {0.f, 0.f, 0.f, 0.f};

    f32x4 acc[4][2];                 // constant-indexed after full unroll
    bf16x8 c0, c1, c2, c3, x0, x1, x2, x3;
    float nj0 = 0.f, nj1 = 0.f;

    // Preload sub-step 0 (t=0, half=0, np=0, kh=0): groups g = 0,1,8,9.
    {
        const unsigned short* tp = Xb + ((size_t)(jo * 4) << 14);
        c0 = *(const bf16x8*)(tp + ((size_t)(0 * 64 + ln) * 8));
        c1 = *(const bf16x8*)(tp + ((size_t)(1 * 64 + ln) * 8));
        c2 = *(const bf16x8*)(tp + ((size_t)(8 * 64 + ln) * 8));
        c3 = *(const bf16x8*)(tp + ((size_t)(9 * 64 + ln) * 8));
    }

    #pragma unroll
    for (int s = 0; s < 32; ++s) {
        const int t    = s >> 3;
        const int half = (s >> 2) & 1;
        const int np   = (s >> 1) & 1;
        const int kh   = s & 1;
        const int jt   = jo * 4 + t;

        // Prefetch sub-step s+1's 4 B-fragments (issued before the MFMAs).
        if (s + 1 < 32) {
            const int s1 = s + 1;
            const int t1 = s1 >> 3, h1 = (s1 >> 2) & 1;
            const int p1 = (s1 >> 1) & 1, k1 = s1 & 1;
            const unsigned short* tp1 = Xb + ((size_t)(jo * 4 + t1) << 14);
            const int gl = (k1 * 2) * 8 + h1 * 4 + p1 * 2;   // ks-lo group
            x0 = *(const bf16x8*)(tp1 + ((size_t)((gl    ) * 64 + ln) * 8));
            x1 = *(const bf16x8*)(tp1 + ((size_t)((gl + 1) * 64 + ln) * 8));
            x2 = *(const bf16x8*)(tp1 + ((size_t)((gl + 8) * 64 + ln) * 8));
            x3 = *(const bf16x8*)(tp1 + ((size_t)((gl + 9) * 64 + ln) * 8));
        }
        if (kh == 0) {   // column norms for this (t,half,np), used at kh==1
            nj0 = sqb[jt * 128 + (half * 4 + np * 2 + 0) * 16 + lr];
            nj1 = sqb[jt * 128 + (half * 4 + np * 2 + 1) * 16 + lr];
        }

        // 16 MFMAs: ks = kh*2 (c0:n0, c1:n1), ks = kh*2+1 (c2, c3).
        #pragma unroll
        for (int m = 0; m < 4; ++m) {
            acc[m][0] = __builtin_amdgcn_mfma_f32_16x16x32_bf16(
                Af[m][kh * 2], c0, kh ? acc[m][0] : zero4, 0, 0, 0);
            acc[m][1] = __builtin_amdgcn_mfma_f32_16x16x32_bf16(
                Af[m][kh * 2], c1, kh ? acc[m][1] : zero4, 0, 0, 0);
        }
        #pragma unroll
        for (int m = 0; m < 4; ++m) {
            acc[m][0] = __builtin_amdgcn_mfma_f32_16x16x32_bf16(
                Af[m][kh * 2 + 1], c2, acc[m][0], 0, 0, 0);
            acc[m][1] = __builtin_amdgcn_mfma_f32_16x16x32_bf16(
                Af[m][kh * 2 + 1], c3, acc[m][1], 0, 0, 0);
        }

        if (kh == 1) {   // epilogue: fold min_j (n_j - 2 g) for this n-pair
            const bool dtile = (jt >> 1) == it;
            if (!dtile) {
                #pragma unroll
                for (int m = 0; m < 4; ++m)
                    #pragma unroll
                    for (int rr = 0; rr < 4; ++rr) {
                        float t0 = fmaf(-2.f, acc[m][0][rr], nj0);
                        float t1 = fmaf(-2.f, acc[m][1][rr], nj1);
                        rmin[m * 4 + rr] =
                            fminf(rmin[m * 4 + rr], fminf(t0, t1));
                    }
            } else {
                #pragma unroll
                for (int m = 0; m < 4; ++m)
                    #pragma unroll
                    for (int rr = 0; rr < 4; ++rr) {
                        int ir = ibase + m * 16 + rg + rr;       // global row
                        int jc = jt * 128 + (half * 4 + np * 2) * 16 + lr;
                        float t0 = (ir == jc)      ? 1e30f
                                   : fmaf(-2.f, acc[m][0][rr], nj0);
                        float t1 = (ir == jc + 16) ? 1e30f
                                   : fmaf(-2.f, acc[m][1][rr], nj1);
                        rmin[m * 4 + rr] =
                            fminf(rmin[m * 4 + rr], fminf(t0, t1));
                    }
            }
        }

        c0 = x0; c1 = x1; c2 = x2; c3 = x3;

        // Tile boundary: raw s_barrier (exec sync only, no memory drain) to
        // keep the WG's 4 waves lockstep so identical B-reads hit L1.
        if ((s & 7) == 7 && s != 31) __builtin_amdgcn_s_barrier();
    }

    // Min across the 16 column-lanes, then one atomicMin per row.
    #pragma unroll
    for (int o = 1; o < 16; o <<= 1)
        #pragma unroll
        for (int q = 0; q < 16; ++q)
            rmin[q] = fminf(rmin[q], __shfl_xor(rmin[q], o, 64));
    if (lr == 0) {
        #pragma unroll
        for (int m = 0; m < 4; ++m)
            #pragma unroll
            for (int rr = 0; rr < 4; ++rr) {
                int row = ibase + m * 16 + rg + rr;
                atomicMin(pmk + b * N_ + row, minkey(rmin[m * 4 + rr]));
            }
    }
}

// ---------------------------------------------------------------------------
// K3: decode keys -> nnd; mean / unbiased std / CV.  64 WGs x 512 thr (one
// pmk load per thread — round-8 lesson: a single-WG reader serializes 32K
// high-latency loads = +40 us).  Last WG sums the 64 slots.
// ---------------------------------------------------------------------------
__global__ __launch_bounds__(512) void finalize_kernel(
        const unsigned* __restrict__ pmk, const float* __restrict__ sqn,
        double* __restrict__ slots, unsigned* __restrict__ fincnt,
        float* __restrict__ out) {
    const int M = B_ * N_;
    int r = blockIdx.x * 512 + (int)threadIdx.x;
    unsigned key = pmk[r];
    unsigned u   = (key & 0x80000000u) ? (key ^ 0x80000000u) : ~key;
    float d2 = sqn[r] + __uint_as_float(u);
    float x32 = sqrtf(fmaxf(d2, 0.f));       // reference uses f32 sqrt too
    double x = (double)x32;
    double s1 = x, s2 = x * x;
    #pragma unroll
    for (int o = 32; o; o >>= 1) {
        s1 += __shfl_down(s1, o, 64);
        s2 += __shfl_down(s2, o, 64);
    }
    __shared__ double a1[8], a2[8];
    int wv = threadIdx.x >> 6, ln = threadIdx.x & 63;
    if (ln == 0) { a1[wv] = s1; a2[wv] = s2; }
    __syncthreads();
    if (threadIdx.x == 0) {
        double S1 = 0.0, S2 = 0.0;
        #pragma unroll
        for (int w = 0; w < 8; ++w) { S1 += a1[w]; S2 += a2[w]; }
        slots[blockIdx.x * 2]     = S1;
        slots[blockIdx.x * 2 + 1] = S2;
        __threadfence();
        unsigned old = atomicAdd(fincnt, 1u);
        if (old == 63u) {
            double T1 = 0.0, T2 = 0.0;
            for (int w = 0; w < 64; ++w) {
                T1 += __hip_atomic_load(&slots[w * 2],     __ATOMIC_RELAXED,
                                        __HIP_MEMORY_SCOPE_AGENT);
                T2 += __hip_atomic_load(&slots[w * 2 + 1], __ATOMIC_RELAXED,
                                        __HIP_MEMORY_SCOPE_AGENT);
            }
            double mean = T1 / M;
            double var  = (T2 - T1 * T1 / M) / (M - 1);
            double stdv = var > 0.0 ? sqrt(var) : 0.0;
            double cv   = (mean > 1e-8) ? stdv / fmax(mean, 1e-8) : 0.0;
            out[0] = (float)mean;
            out[1] = (float)stdv;
            out[2] = (float)cv;
        }
    }
}

extern "C" void kernel_launch(void* const* d_in, const int* in_sizes, int n_in,
                              void* d_out, int out_size, void* d_ws, size_t ws_size,
                              hipStream_t stream) {
    const float* X = (const float*)d_in[0];
    const size_t XS_BYTES = (size_t)B_ * N_ * D_ * 2;        // 8 MB
    char* ws = (char*)d_ws;
    unsigned short* Xs     = (unsigned short*)ws;
    float*          sqn    = (float*)(ws + XS_BYTES);
    unsigned*       pmk    = (unsigned*)(ws + XS_BYTES + (size_t)B_ * N_ * 4);
    double*         slots  = (double*)(ws + XS_BYTES + (size_t)B_ * N_ * 8);
    unsigned*       fincnt = (unsigned*)(ws + XS_BYTES + (size_t)B_ * N_ * 8 + 1024);
    float*          out    = (float*)d_out;

    prep_kernel<<<B_ * N_ / 16, 256, 0, stream>>>(X, Xs, sqn, pmk, fincnt);
    nnd_kernel<<<512, 256, 0, stream>>>(Xs, sqn, pmk);
    finalize_kernel<<<B_ * N_ / 512, 512, 0, stream>>>(pmk, sqn, slots, fincnt, out);
}